// Round 7
// baseline (309.496 us; speedup 1.0000x reference)
//
#include <hip/hip_runtime.h>
#include <hip/hip_cooperative_groups.h>

namespace cg = cooperative_groups;

#define BB 32
#define NN 1024
#define FF 7
#define HID 256
#define MLPH 64
#define OUTN 8
#define CATN (MLPH + HID + 8)   // 328

__device__ __forceinline__ float wave_sum(float v) {
#pragma unroll
    for (int m = 32; m >= 1; m >>= 1) v += __shfl_xor(v, m, 64);
    return v;
}
__device__ __forceinline__ float wave_max(float v) {
#pragma unroll
    for (int m = 32; m >= 1; m >>= 1) v = fmaxf(v, __shfl_xor(v, m, 64));
    return v;
}

// ============================ cooperative single kernel ======================
// grid = 512 blocks x 256 thr, launch_bounds(256,4) -> <=128 VGPR, 2 blocks/CU
// needed vs >=4 available (2x margin for coop validation).
__global__ __launch_bounds__(256, 4) void kAll(
    const float* __restrict__ x,
    const float* __restrict__ W1,  const float* __restrict__ b1,
    const float* __restrict__ W2,  const float* __restrict__ b2,
    const float* __restrict__ Wfc, const float* __restrict__ bfc,
    const float* __restrict__ Wg,  const float* __restrict__ bg,
    const float* __restrict__ Wm0, const float* __restrict__ bm0,
    const float* __restrict__ Wm1, const float* __restrict__ bm1,
    const float* __restrict__ Wp,  const float* __restrict__ bp,
    float* ws, float* __restrict__ out) {
    __shared__ __align__(16) float sx[1792];   // one 256-node x-window (7 fields)
    __shared__ __align__(16) float s0[256];
    __shared__ __align__(16) float s1[256];
    __shared__ __align__(16) float s2[256];
    __shared__ __align__(16) float s3[256];
    __shared__ __align__(16) float s4[256];
    __shared__ __align__(16) float s5[256];
    __shared__ float wred[4];

    float* degp  = ws;            // [4][32][1024]
    float* q0p   = ws + 131072;
    float* q1p   = ws + 262144;
    float* wjp   = ws + 393216;
    float* hp    = ws + 524288;   // [4][32][256]
    float* mlp_p = ws + 557056;   // [8192]
    float* bmaxw = ws + 565248;   // [32*64]
    float* sumsp = ws + 567296;   // [32]
    float* xf2   = ws + 567328;   // [32*64]
    float* sglo  = ws + 569376;   // [32*8]
    float* E     = ws + 569632;   // [8*256]
    float* cE    = ws + 571680;   // [8]

    cg::grid_group grid = cg::this_grid();
    int blk = blockIdx.x, tid = threadIdx.x, lane = tid & 63, w = tid >> 6;

    // ---------- Phase 1: pass1 (4 units/block) + MLP-L1 chunks + speed sums ----
    for (int u = 0; u < 4; ++u) {
        int unit = blk * 4 + u;                 // [0,2048)
        int b = unit >> 6, jg = (unit >> 2) & 15, ks = unit & 3;
        const float* xb = x + b * (NN * FF);
        {   // coalesced stage of the unit's 256-node window (448 float4)
            const float4* xw4 = (const float4*)(xb + ks * 1792);
            float4* sx4 = (float4*)sx;
            sx4[tid] = xw4[tid];
            if (tid < 192) sx4[256 + tid] = xw4[256 + tid];
        }
        int j = jg * 64 + lane;
        float pj0 = xb[j * FF + 1];
        float pj1 = xb[j * FF + 2];
        __syncthreads();
        s0[tid] = sx[tid * 7 + 1];   // stride-7 over 32 banks: 2-way, free
        s1[tid] = sx[tid * 7 + 2];
        __syncthreads();
        const float4* v0p = (const float4*)&s0[w * 64];
        const float4* v1p = (const float4*)&s1[w * 64];
        unsigned degv = 0u;
        float mx = 0.f;
#pragma unroll 4
        for (int g = 0; g < 16; ++g) {
            float4 v0 = v0p[g], v1 = v1p[g];
            float dxa = pj0 - v0.x, dya = pj1 - v1.x;
            float dxb = pj0 - v0.y, dyb = pj1 - v1.y;
            float dxc = pj0 - v0.z, dyc = pj1 - v1.z;
            float dxd = pj0 - v0.w, dyd = pj1 - v1.w;
            float da = fmaf(dya, dya, dxa * dxa);
            float db = fmaf(dyb, dyb, dxb * dxb);
            float dc = fmaf(dyc, dyc, dxc * dxc);
            float dd = fmaf(dyd, dyd, dxd * dxd);
            degv += (da <= 0.09f);
            degv += (db <= 0.09f);
            degv += (dc <= 0.09f);
            degv += (dd <= 0.09f);
            mx = fmaxf(fmaxf(mx, fmaxf(da, db)), fmaxf(dc, dd));
        }
        s2[tid] = (float)degv;
        __syncthreads();
        if (tid < 64) {
            degp[ks * (BB * NN) + b * NN + jg * 64 + tid] =
                s2[tid] + s2[tid + 64] + s2[tid + 128] + s2[tid + 192];
        }
        mx = wave_max(mx);
        if (lane == 0) wred[w] = mx;
        __syncthreads();
        if (tid == 0)
            bmaxw[b * 64 + jg * 4 + ks] =
                fmaxf(fmaxf(wred[0], wred[1]), fmaxf(wred[2], wred[3]));
        // MLP layer-1 partial: one 1792-elt chunk per wave
        {
            int id = unit * 4 + w;              // [0,8192)
            int mb = id >> 8, mh = (id >> 2) & 63, mc = id & 3;
            const float4* wr = (const float4*)(Wm0 + mh * (NN * FF) + mc * 1792);
            const float4* xr = (const float4*)(x + mb * (NN * FF) + mc * 1792);
            float4 a4 = {0.f, 0.f, 0.f, 0.f};
#pragma unroll
            for (int it = 0; it < 7; ++it) {
                float4 wv = wr[it * 64 + lane];
                float4 xv = xr[it * 64 + lane];
                a4.x = fmaf(wv.x, xv.x, a4.x);
                a4.y = fmaf(wv.y, xv.y, a4.y);
                a4.z = fmaf(wv.z, xv.z, a4.z);
                a4.w = fmaf(wv.w, xv.w, a4.w);
            }
            float s = (a4.x + a4.y) + (a4.z + a4.w);
            s = wave_sum(s);
            if (lane == 0) mlp_p[id] = s;
        }
        if (jg == 0 && ks == 0) {   // 32 units own the per-batch speed sum
            float sp = 0.f;
            for (int nn = tid; nn < NN; nn += 256) {
                float vx = xb[nn * FF + 3], vy = xb[nn * FF + 4];
                sp += sqrtf(vx * vx + vy * vy);
            }
            sp = wave_sum(sp);
            __syncthreads();
            if (lane == 0) wred[w] = sp;
            __syncthreads();
            if (tid == 0) sumsp[b] = wred[0] + wred[1] + wred[2] + wred[3];
        }
        __syncthreads();
    }
    grid.sync();
    // ---------- Phase 2: pass2 (4 units/block) -------------------------------
    for (int u = 0; u < 4; ++u) {
        int unit = blk * 4 + u;
        int b = unit >> 6, jg = (unit >> 2) & 15, ks = unit & 3;
        const float* xb = x + b * (NN * FF);
        {
            const float4* xw4 = (const float4*)(xb + ks * 1792);
            float4* sx4 = (float4*)sx;
            sx4[tid] = xw4[tid];
            if (tid < 192) sx4[256 + tid] = xw4[256 + tid];
        }
        {
            int o = b * NN + ks * 256 + tid;
            float d = degp[o] + degp[BB * NN + o] + degp[2 * BB * NN + o]
                    + degp[3 * BB * NN + o];
            s2[tid] = 1.0f / sqrtf(d);
        }
        int j = jg * 64 + lane;
        float pj0 = xb[j * FF + 1];
        float pj1 = xb[j * FF + 2];
        __syncthreads();
        s0[tid] = sx[tid * 7 + 1];
        s1[tid] = sx[tid * 7 + 2];
        __syncthreads();
        const float4* v0p = (const float4*)&s0[w * 64];
        const float4* v1p = (const float4*)&s1[w * 64];
        const float4* vdp = (const float4*)&s2[w * 64];
        float a0 = 0.f, a1 = 0.f, as = 0.f;
#pragma unroll 4
        for (int g = 0; g < 16; ++g) {
            float4 v0 = v0p[g], v1 = v1p[g], vd = vdp[g];
            float dxa = pj0 - v0.x, dya = pj1 - v1.x;
            float dxb = pj0 - v0.y, dyb = pj1 - v1.y;
            float dxc = pj0 - v0.z, dyc = pj1 - v1.z;
            float dxd = pj0 - v0.w, dyd = pj1 - v1.w;
            float da = fmaf(dya, dya, dxa * dxa);
            float db = fmaf(dyb, dyb, dxb * dxb);
            float dc = fmaf(dyc, dyc, dxc * dxc);
            float dd = fmaf(dyd, dyd, dxd * dxd);
            float ta = (da <= 0.09f) ? vd.x : 0.0f;
            float tb = (db <= 0.09f) ? vd.y : 0.0f;
            float tc = (dc <= 0.09f) ? vd.z : 0.0f;
            float td = (dd <= 0.09f) ? vd.w : 0.0f;
            a0 = fmaf(ta, v0.x, a0); a1 = fmaf(ta, v1.x, a1); as += ta;
            a0 = fmaf(tb, v0.y, a0); a1 = fmaf(tb, v1.y, a1); as += tb;
            a0 = fmaf(tc, v0.z, a0); a1 = fmaf(tc, v1.z, a1); as += tc;
            a0 = fmaf(td, v0.w, a0); a1 = fmaf(td, v1.w, a1); as += td;
        }
        s3[tid] = a0; s4[tid] = a1; s5[tid] = as;
        __syncthreads();
        if (tid < 64) {
            int jj = jg * 64 + tid;
            int o = b * NN + jj;
            float d = degp[o] + degp[BB * NN + o] + degp[2 * BB * NN + o]
                    + degp[3 * BB * NN + o];
            float dj = 1.0f / sqrtf(d);
            float q0v = s3[tid] + s3[tid + 64] + s3[tid + 128] + s3[tid + 192];
            float q1v = s4[tid] + s4[tid + 64] + s4[tid + 128] + s4[tid + 192];
            float ssv = s5[tid] + s5[tid + 64] + s5[tid + 128] + s5[tid + 192];
            int oo = ks * (BB * NN) + b * NN + jj;
            q0p[oo] = dj * q0v;
            q1p[oo] = dj * q1v;
            wjp[oo] = dj * ssv * (1.0f / NN);
        }
        __syncthreads();
    }
    grid.sync();
    // ---------- Phase 3: hsum(0-127) + xf2(128-135) + glo(136-167) + collapse(168-175)
    if (blk < 128) {
        int b = blk >> 2, jq = blk & 3;
        int o = b * NN + jq * 256 + tid;
        s0[tid] = q0p[o] + q0p[BB * NN + o] + q0p[2 * BB * NN + o] + q0p[3 * BB * NN + o];
        s1[tid] = q1p[o] + q1p[BB * NN + o] + q1p[2 * BB * NN + o] + q1p[3 * BB * NN + o];
        s2[tid] = wjp[o] + wjp[BB * NN + o] + wjp[2 * BB * NN + o] + wjp[3 * BB * NN + o];
        __syncthreads();
        float w10 = W1[tid * 2], w11 = W1[tid * 2 + 1], bb = b1[tid];
        float acc = 0.f;
        const float4* q0v4 = (const float4*)s0;
        const float4* q1v4 = (const float4*)s1;
        const float4* wv4  = (const float4*)s2;
#pragma unroll 4
        for (int g = 0; g < 64; ++g) {
            float4 q0v = q0v4[g], q1v = q1v4[g], wv = wv4[g];
            acc = fmaf(wv.x, fmaxf(fmaf(q1v.x, w11, fmaf(q0v.x, w10, bb)), 0.f), acc);
            acc = fmaf(wv.y, fmaxf(fmaf(q1v.y, w11, fmaf(q0v.y, w10, bb)), 0.f), acc);
            acc = fmaf(wv.z, fmaxf(fmaf(q1v.z, w11, fmaf(q0v.z, w10, bb)), 0.f), acc);
            acc = fmaf(wv.w, fmaxf(fmaf(q1v.w, w11, fmaf(q0v.w, w10, bb)), 0.f), acc);
        }
        hp[jq * (BB * HID) + b * HID + tid] = acc;
    } else if (blk < 136) {
        int b = (blk - 128) * 4 + (tid >> 6), h = lane;
        float4 p = *(const float4*)&mlp_p[(b * 64 + h) * 4];
        s0[tid] = fmaxf(((p.x + p.y) + (p.z + p.w)) + bm0[h], 0.f);
        __syncthreads();
        float a = bm1[h];
        const float* wv = Wm1 + h * MLPH;
        const float* xv = &s0[(tid >> 6) * 64];
#pragma unroll
        for (int k = 0; k < MLPH; ++k) a = fmaf(wv[k], xv[k], a);
        xf2[b * 64 + h] = fmaxf(a, 0.f);
    } else if (blk < 168) {
        int b = blk - 136;
        if (tid < 64) {
            float v = bmaxw[b * 64 + tid];
            v = wave_max(v);
            if (tid < 8) {
                float avg  = sumsp[b] * (1.0f / NN);
                float dens = 1.0f / sqrtf(v);
                sglo[b * 8 + tid] =
                    fmaxf(fmaf(Wg[tid * 2], avg, fmaf(Wg[tid * 2 + 1], dens, bg[tid])), 0.f);
            }
        }
    } else if (blk < 176) {
        int o = blk - 168;   // E = (Wp_gcn@Wfc)@W2, cE
        s0[tid] = Wp[o * CATN + MLPH + tid];
        __syncthreads();
        float a = 0.f;
#pragma unroll 8
        for (int m = 0; m < HID; ++m) a = fmaf(s0[m], Wfc[m * HID + tid], a);
        s1[tid] = a;
        s2[tid] = s0[tid] * bfc[tid];
        __syncthreads();
        float e = 0.f;
#pragma unroll 8
        for (int k = 0; k < HID; ++k) e = fmaf(s1[k], W2[k * HID + tid], e);
        E[o * HID + tid] = e;
        float c = fmaf(s1[tid], b2[tid], s2[tid]);
        c = wave_sum(c);
        if (lane == 0) wred[w] = c;
        __syncthreads();
        if (tid == 0) cE[o] = wred[0] + wred[1] + wred[2] + wred[3];
    }
    grid.sync();
    // ---------- Phase 4: final output, 32 blocks ------------------------------
    if (blk < 32) {
        int b = blk;
        {
            int o = b * HID + tid;
            s0[tid] = hp[o] + hp[BB * HID + o] + hp[2 * BB * HID + o]
                    + hp[3 * BB * HID + o];
        }
        if (tid < 64) s1[tid] = xf2[b * 64 + tid];
        if (tid < 8)  s2[tid] = sglo[b * 8 + tid];
        __syncthreads();
        int oo = w;
#pragma unroll
        for (int rep = 0; rep < 2; ++rep) {
            const float* Eo = E + oo * HID;
            float a = Eo[lane] * s0[lane];
            a = fmaf(Eo[lane + 64],  s0[lane + 64],  a);
            a = fmaf(Eo[lane + 128], s0[lane + 128], a);
            a = fmaf(Eo[lane + 192], s0[lane + 192], a);
            a = fmaf(Wp[oo * CATN + lane], s1[lane], a);
            a = wave_sum(a);
            if (lane == 0) {
                const float* wg = Wp + oo * CATN + MLPH + HID;
#pragma unroll
                for (int g = 0; g < 8; ++g) a = fmaf(wg[g], s2[g], a);
                out[b * OUTN + oo] = a + cE[oo] + bp[oo];
            }
            oo += 4;
        }
    }
}

// ============================ fallback: R5 three-kernel path =================
__global__ __launch_bounds__(256) void kA(const float* __restrict__ x,
                                          const float* __restrict__ Wm0,
                                          const float* __restrict__ bm0,
                                          const float* __restrict__ W2,
                                          const float* __restrict__ b2,
                                          const float* __restrict__ Wfc,
                                          const float* __restrict__ bfc,
                                          const float* __restrict__ Wp,
                                          float* __restrict__ degp,
                                          float* __restrict__ bmax,
                                          float* __restrict__ sumsp,
                                          float* __restrict__ xf1,
                                          float* __restrict__ E,
                                          float* __restrict__ cE) {
    __shared__ __align__(16) float l0[256];
    __shared__ __align__(16) float l1[256];
    __shared__ float red[256];
    __shared__ float wred[4];
    int tid = threadIdx.x, lane = tid & 63, w = tid >> 6;
    if (blockIdx.x < 2048) {
        int blk = blockIdx.x;
        int b = blk >> 6, jg = (blk >> 2) & 15, ks = blk & 3;
        const float* xb = x + b * (NN * FF);
        int n = ks * 256 + tid;
        l0[tid] = xb[n * FF + 1];
        l1[tid] = xb[n * FF + 2];
        int j = jg * 64 + lane;
        float pj0 = xb[j * FF + 1];
        float pj1 = xb[j * FF + 2];
        __syncthreads();
        const float4* v0p = (const float4*)&l0[w * 64];
        const float4* v1p = (const float4*)&l1[w * 64];
        unsigned degv = 0u;
        float mx = 0.f;
#pragma unroll 4
        for (int g = 0; g < 16; ++g) {
            float4 v0 = v0p[g], v1 = v1p[g];
            float dxa = pj0 - v0.x, dya = pj1 - v1.x;
            float dxb = pj0 - v0.y, dyb = pj1 - v1.y;
            float dxc = pj0 - v0.z, dyc = pj1 - v1.z;
            float dxd = pj0 - v0.w, dyd = pj1 - v1.w;
            float da = fmaf(dya, dya, dxa * dxa);
            float db = fmaf(dyb, dyb, dxb * dxb);
            float dc = fmaf(dyc, dyc, dxc * dxc);
            float dd = fmaf(dyd, dyd, dxd * dxd);
            degv += (da <= 0.09f);
            degv += (db <= 0.09f);
            degv += (dc <= 0.09f);
            degv += (dd <= 0.09f);
            mx = fmaxf(fmaxf(mx, fmaxf(da, db)), fmaxf(dc, dd));
        }
        red[tid] = (float)degv;
        __syncthreads();
        if (tid < 64) {
            degp[ks * (BB * NN) + b * NN + jg * 64 + tid] =
                red[tid] + red[tid + 64] + red[tid + 128] + red[tid + 192];
        }
        mx = wave_max(mx);
        if (lane == 0) wred[w] = mx;
        __syncthreads();
        if (tid == 0)
            bmax[b * 64 + jg * 4 + ks] =
                fmaxf(fmaxf(wred[0], wred[1]), fmaxf(wred[2], wred[3]));
        if (jg == 0 && ks == 0) {
            float sp = 0.f;
            for (int nn = tid; nn < NN; nn += 256) {
                float vx = xb[nn * FF + 3], vy = xb[nn * FF + 4];
                sp += sqrtf(vx * vx + vy * vy);
            }
            sp = wave_sum(sp);
            __syncthreads();
            if (lane == 0) wred[w] = sp;
            __syncthreads();
            if (tid == 0) sumsp[b] = wred[0] + wred[1] + wred[2] + wred[3];
        }
    } else if (blockIdx.x < 2560) {
        int blk = blockIdx.x - 2048;
        int b = blk >> 4, hq = blk & 15;
        int h = hq * 4 + w;
        const float4* wrow = (const float4*)(Wm0 + h * (NN * FF));
        const float4* xrow = (const float4*)(x + b * (NN * FF));
        float4 a4 = {0.f, 0.f, 0.f, 0.f};
#pragma unroll 7
        for (int it = 0; it < 28; ++it) {
            float4 wv = wrow[it * 64 + lane];
            float4 xv = xrow[it * 64 + lane];
            a4.x = fmaf(wv.x, xv.x, a4.x);
            a4.y = fmaf(wv.y, xv.y, a4.y);
            a4.z = fmaf(wv.z, xv.z, a4.z);
            a4.w = fmaf(wv.w, xv.w, a4.w);
        }
        float s = (a4.x + a4.y) + (a4.z + a4.w);
        s = wave_sum(s);
        if (lane == 0) xf1[b * MLPH + h] = fmaxf(s + bm0[h], 0.f);
    } else {
        int o = blockIdx.x - 2560;
        l0[tid] = Wp[o * CATN + MLPH + tid];
        __syncthreads();
        float a = 0.f;
#pragma unroll 8
        for (int m = 0; m < HID; ++m) a = fmaf(l0[m], Wfc[m * HID + tid], a);
        l1[tid] = a;
        red[tid] = l0[tid] * bfc[tid];
        __syncthreads();
        float e = 0.f;
#pragma unroll 8
        for (int k = 0; k < HID; ++k) e = fmaf(l1[k], W2[k * HID + tid], e);
        E[o * HID + tid] = e;
        float c = fmaf(l1[tid], b2[tid], red[tid]);
        c = wave_sum(c);
        if (lane == 0) wred[w] = c;
        __syncthreads();
        if (tid == 0) cE[o] = wred[0] + wred[1] + wred[2] + wred[3];
    }
}

__global__ __launch_bounds__(256) void kB(const float* __restrict__ x,
                                          const float* __restrict__ degp,
                                          float* __restrict__ q0p,
                                          float* __restrict__ q1p,
                                          float* __restrict__ wjp) {
    __shared__ __align__(16) float l0[256];
    __shared__ __align__(16) float l1[256];
    __shared__ __align__(16) float di[256];
    __shared__ float r0[256], r1[256], r2[256];
    int blk = blockIdx.x;
    int b = blk >> 6, jg = (blk >> 2) & 15, ks = blk & 3;
    int tid = threadIdx.x, lane = tid & 63, w = tid >> 6;
    const float* xb = x + b * (NN * FF);
    int n = ks * 256 + tid;
    l0[tid] = xb[n * FF + 1];
    l1[tid] = xb[n * FF + 2];
    {
        int o = b * NN + n;
        float d = degp[o] + degp[BB * NN + o] + degp[2 * BB * NN + o] + degp[3 * BB * NN + o];
        di[tid] = 1.0f / sqrtf(d);
    }
    int j = jg * 64 + lane;
    float pj0 = xb[j * FF + 1];
    float pj1 = xb[j * FF + 2];
    __syncthreads();
    const float4* v0p = (const float4*)&l0[w * 64];
    const float4* v1p = (const float4*)&l1[w * 64];
    const float4* vdp = (const float4*)&di[w * 64];
    float a0 = 0.f, a1 = 0.f, as = 0.f;
#pragma unroll 4
    for (int g = 0; g < 16; ++g) {
        float4 v0 = v0p[g], v1 = v1p[g], vd = vdp[g];
        float dxa = pj0 - v0.x, dya = pj1 - v1.x;
        float dxb = pj0 - v0.y, dyb = pj1 - v1.y;
        float dxc = pj0 - v0.z, dyc = pj1 - v1.z;
        float dxd = pj0 - v0.w, dyd = pj1 - v1.w;
        float da = fmaf(dya, dya, dxa * dxa);
        float db = fmaf(dyb, dyb, dxb * dxb);
        float dc = fmaf(dyc, dyc, dxc * dxc);
        float dd = fmaf(dyd, dyd, dxd * dxd);
        float ta = (da <= 0.09f) ? vd.x : 0.0f;
        float tb = (db <= 0.09f) ? vd.y : 0.0f;
        float tc = (dc <= 0.09f) ? vd.z : 0.0f;
        float td = (dd <= 0.09f) ? vd.w : 0.0f;
        a0 = fmaf(ta, v0.x, a0); a1 = fmaf(ta, v1.x, a1); as += ta;
        a0 = fmaf(tb, v0.y, a0); a1 = fmaf(tb, v1.y, a1); as += tb;
        a0 = fmaf(tc, v0.z, a0); a1 = fmaf(tc, v1.z, a1); as += tc;
        a0 = fmaf(td, v0.w, a0); a1 = fmaf(td, v1.w, a1); as += td;
    }
    r0[tid] = a0; r1[tid] = a1; r2[tid] = as;
    __syncthreads();
    if (tid < 64) {
        int jj = jg * 64 + tid;
        int o = b * NN + jj;
        float d = degp[o] + degp[BB * NN + o] + degp[2 * BB * NN + o] + degp[3 * BB * NN + o];
        float dj = 1.0f / sqrtf(d);
        float s0v = r0[tid] + r0[tid + 64] + r0[tid + 128] + r0[tid + 192];
        float s1v = r1[tid] + r1[tid + 64] + r1[tid + 128] + r1[tid + 192];
        float ssv = r2[tid] + r2[tid + 64] + r2[tid + 128] + r2[tid + 192];
        int oo = ks * (BB * NN) + b * NN + jj;
        q0p[oo] = dj * s0v;
        q1p[oo] = dj * s1v;
        wjp[oo] = dj * ssv * (1.0f / NN);
    }
}

__global__ __launch_bounds__(1024) void kF(const float* __restrict__ q0p,
                                           const float* __restrict__ q1p,
                                           const float* __restrict__ wjp,
                                           const float* __restrict__ W1,
                                           const float* __restrict__ b1,
                                           const float* __restrict__ Wg,
                                           const float* __restrict__ bg,
                                           const float* __restrict__ Wm1,
                                           const float* __restrict__ bm1,
                                           const float* __restrict__ Wp,
                                           const float* __restrict__ bp,
                                           const float* __restrict__ xf1,
                                           const float* __restrict__ bmax,
                                           const float* __restrict__ sumsp,
                                           const float* __restrict__ E,
                                           const float* __restrict__ cE,
                                           float* __restrict__ out) {
    __shared__ __align__(16) float sq0[NN];
    __shared__ __align__(16) float sq1[NN];
    __shared__ __align__(16) float sw[NN];
    __shared__ __align__(16) float hpp[4][HID];
    __shared__ __align__(16) float hs[HID];
    __shared__ float sx1[MLPH];
    __shared__ float sxf2[MLPH];
    __shared__ float sglo[8];
    __shared__ float smax;
    int b = blockIdx.x, tid = threadIdx.x;
    {
        int o = b * NN + tid;
        sq0[tid] = q0p[o] + q0p[BB * NN + o] + q0p[2 * BB * NN + o] + q0p[3 * BB * NN + o];
        sq1[tid] = q1p[o] + q1p[BB * NN + o] + q1p[2 * BB * NN + o] + q1p[3 * BB * NN + o];
        sw[tid]  = wjp[o] + wjp[BB * NN + o] + wjp[2 * BB * NN + o] + wjp[3 * BB * NN + o];
    }
    if (tid >= 384 && tid < 448) {
        float v = bmax[b * 64 + (tid - 384)];
        v = wave_max(v);
        if (tid == 384) smax = v;
    }
    if (tid >= 448 && tid < 512) sx1[tid - 448] = xf1[b * MLPH + (tid - 448)];
    __syncthreads();
    {
        int h = tid & 255, jq = tid >> 8;
        float w10 = W1[h * 2], w11 = W1[h * 2 + 1], bb = b1[h];
        float acc = 0.f;
        const float4* q0v4 = (const float4*)&sq0[jq * 256];
        const float4* q1v4 = (const float4*)&sq1[jq * 256];
        const float4* wv4  = (const float4*)&sw[jq * 256];
#pragma unroll 4
        for (int g = 0; g < 64; ++g) {
            float4 q0v = q0v4[g], q1v = q1v4[g], wv = wv4[g];
            acc = fmaf(wv.x, fmaxf(fmaf(q1v.x, w11, fmaf(q0v.x, w10, bb)), 0.f), acc);
            acc = fmaf(wv.y, fmaxf(fmaf(q1v.y, w11, fmaf(q0v.y, w10, bb)), 0.f), acc);
            acc = fmaf(wv.z, fmaxf(fmaf(q1v.z, w11, fmaf(q0v.z, w10, bb)), 0.f), acc);
            acc = fmaf(wv.w, fmaxf(fmaf(q1v.w, w11, fmaf(q0v.w, w10, bb)), 0.f), acc);
        }
        hpp[jq][h] = acc;
    }
    __syncthreads();
    if (tid < HID) {
        hs[tid] = hpp[0][tid] + hpp[1][tid] + hpp[2][tid] + hpp[3][tid];
    } else if (tid < HID + MLPH) {
        int t = tid - HID;
        float a = bm1[t];
        const float* wv = Wm1 + t * MLPH;
#pragma unroll
        for (int k = 0; k < MLPH; ++k) a = fmaf(wv[k], sx1[k], a);
        sxf2[t] = fmaxf(a, 0.f);
    } else if (tid < HID + MLPH + 8) {
        int t = tid - HID - MLPH;
        float avg  = sumsp[b] * (1.0f / NN);
        float dens = 1.0f / sqrtf(smax);
        sglo[t] = fmaxf(fmaf(Wg[t * 2], avg, fmaf(Wg[t * 2 + 1], dens, bg[t])), 0.f);
    }
    __syncthreads();
    if (tid < 512) {
        int o = tid >> 6, lane = tid & 63;
        const float* Eo = E + o * HID;
        float a = Eo[lane] * hs[lane];
        a = fmaf(Eo[lane + 64],  hs[lane + 64],  a);
        a = fmaf(Eo[lane + 128], hs[lane + 128], a);
        a = fmaf(Eo[lane + 192], hs[lane + 192], a);
        a = fmaf(Wp[o * CATN + lane], sxf2[lane], a);
        a = wave_sum(a);
        if (lane == 0) {
            const float* wg = Wp + o * CATN + MLPH + HID;
#pragma unroll
            for (int g = 0; g < 8; ++g) a = fmaf(wg[g], sglo[g], a);
            out[b * OUTN + o] = a + cE[o] + bp[o];
        }
    }
}

extern "C" void kernel_launch(void* const* d_in, const int* in_sizes, int n_in,
                              void* d_out, int out_size, void* d_ws, size_t ws_size,
                              hipStream_t stream) {
    const float* x   = (const float*)d_in[0];
    const float* W1  = (const float*)d_in[1];
    const float* b1  = (const float*)d_in[2];
    const float* W2  = (const float*)d_in[3];
    const float* b2  = (const float*)d_in[4];
    const float* Wfc = (const float*)d_in[5];
    const float* bfc = (const float*)d_in[6];
    const float* Wg  = (const float*)d_in[7];
    const float* bg  = (const float*)d_in[8];
    const float* Wm0 = (const float*)d_in[9];
    const float* bm0 = (const float*)d_in[10];
    const float* Wm1 = (const float*)d_in[11];
    const float* bm1 = (const float*)d_in[12];
    const float* Wp  = (const float*)d_in[13];
    const float* bp  = (const float*)d_in[14];
    float* out = (float*)d_out;
    float* ws  = (float*)d_ws;

    // Deterministic path choice: coop only if the runtime can co-schedule 512 blocks.
    int nb = 0;
    hipError_t qe = hipOccupancyMaxActiveBlocksPerMultiprocessor(
        &nb, reinterpret_cast<const void*>(&kAll), 256, 0);
    if (qe == hipSuccess && nb >= 2) {
        void* args[] = {
            (void*)&x,
            (void*)&W1,  (void*)&b1,
            (void*)&W2,  (void*)&b2,
            (void*)&Wfc, (void*)&bfc,
            (void*)&Wg,  (void*)&bg,
            (void*)&Wm0, (void*)&bm0,
            (void*)&Wm1, (void*)&bm1,
            (void*)&Wp,  (void*)&bp,
            (void*)&ws,  (void*)&out,
        };
        hipError_t le = hipLaunchCooperativeKernel((void*)kAll, dim3(512), dim3(256),
                                                   args, 0, stream);
        if (le == hipSuccess) return;
    }
    // Fallback: known-good three-dispatch path (R5 layout).
    float* degp  = ws;            // 131072
    float* q0p   = ws + 131072;   // 131072
    float* q1p   = ws + 262144;   // 131072
    float* wjp   = ws + 393216;   // 131072
    float* bmax  = ws + 524288;   // 2048
    float* sumsp = ws + 526336;   // 32
    float* xf1   = ws + 526368;   // 2048
    float* E     = ws + 528416;   // 2048
    float* cE    = ws + 530464;   // 8
    kA<<<2568,    256,  0, stream>>>(x, Wm0, bm0, W2, b2, Wfc, bfc, Wp,
                                     degp, bmax, sumsp, xf1, E, cE);
    kB<<<BB * 64, 256,  0, stream>>>(x, degp, q0p, q1p, wjp);
    kF<<<BB,      1024, 0, stream>>>(q0p, q1p, wjp, W1, b1, Wg, bg,
                                     Wm1, bm1, Wp, bp,
                                     xf1, bmax, sumsp, E, cE, out);
}

// Round 8
// 132.425 us; speedup vs baseline: 2.3371x; 2.3371x over previous
//
#include <hip/hip_runtime.h>

#define BB 32
#define NN 1024
#define FF 7
#define HID 256
#define MLPH 64
#define OUTN 8
#define CATN (MLPH + HID + 8)   // 328

__device__ __forceinline__ float wave_sum(float v) {
#pragma unroll
    for (int m = 32; m >= 1; m >>= 1) v += __shfl_xor(v, m, 64);
    return v;
}
__device__ __forceinline__ float wave_max(float v) {
#pragma unroll
    for (int m = 32; m >= 1; m >>= 1) v = fmaxf(v, __shfl_xor(v, m, 64));
    return v;
}

// kA: blocks [0,512): unit (b = blk>>4, jg = blk&15) — pass1 over 64 j x ALL 1024 k.
//     Produces FINAL deg[b][j], bmaxp[b][jg], spd[b][jg], + 16 MLP-L1 chunks (1/wave).
//     blocks [512,520): weight collapse E = (Wp_gcn@Wfc)@W2, cE.
// 1024 thr/block = 16 waves -> >=16 waves/CU resident even at 1 block/CU.
__global__ __launch_bounds__(1024, 8) void kA(const float* __restrict__ x,
                                              const float* __restrict__ Wm0,
                                              const float* __restrict__ W2,
                                              const float* __restrict__ b2,
                                              const float* __restrict__ Wfc,
                                              const float* __restrict__ bfc,
                                              const float* __restrict__ Wp,
                                              float* __restrict__ deg,
                                              float* __restrict__ bmaxp,
                                              float* __restrict__ spd,
                                              float* __restrict__ mlp_p,
                                              float* __restrict__ E,
                                              float* __restrict__ cE) {
    __shared__ __align__(16) float l0[NN];
    __shared__ __align__(16) float l1[NN];
    __shared__ __align__(16) float red[NN];
    __shared__ float wred[16];
    int blk = blockIdx.x, tid = threadIdx.x, lane = tid & 63, w = tid >> 6;
    if (blk < 512) {
        int b = blk >> 4, jg = blk & 15;
        const float* xb = x + b * (NN * FF);
        l0[tid] = xb[tid * FF + 1];
        l1[tid] = xb[tid * FF + 2];
        __syncthreads();
        int j = jg * 64 + lane;
        float pj0 = l0[j], pj1 = l1[j];
        const float4* v0p = (const float4*)&l0[w * 64];   // wave w owns k-chunk w
        const float4* v1p = (const float4*)&l1[w * 64];
        unsigned degv = 0u;
        float mx = 0.f;
#pragma unroll 4
        for (int g = 0; g < 16; ++g) {
            float4 v0 = v0p[g], v1 = v1p[g];
            float dxa = pj0 - v0.x, dya = pj1 - v1.x;
            float dxb = pj0 - v0.y, dyb = pj1 - v1.y;
            float dxc = pj0 - v0.z, dyc = pj1 - v1.z;
            float dxd = pj0 - v0.w, dyd = pj1 - v1.w;
            float da = fmaf(dya, dya, dxa * dxa);
            float db = fmaf(dyb, dyb, dxb * dxb);
            float dc = fmaf(dyc, dyc, dxc * dxc);
            float dd = fmaf(dyd, dyd, dxd * dxd);
            degv += (da <= 0.09f);
            degv += (db <= 0.09f);
            degv += (dc <= 0.09f);
            degv += (dd <= 0.09f);
            mx = fmaxf(fmaxf(mx, fmaxf(da, db)), fmaxf(dc, dd));
        }
        red[tid] = (float)degv;
        mx = wave_max(mx);
        if (lane == 0) wred[w] = mx;
        __syncthreads();
        if (tid < 64) {
            float s = 0.f;
#pragma unroll
            for (int kk = 0; kk < 16; ++kk) s += red[kk * 64 + tid];
            deg[b * NN + jg * 64 + tid] = s;
        }
        if (tid == 0) {
            float m = wred[0];
#pragma unroll
            for (int i = 1; i < 16; ++i) m = fmaxf(m, wred[i]);
            bmaxp[b * 16 + jg] = m;
        }
        if (w == 1) {   // wave 1: speed partial for this jg's 64 nodes
            int n = jg * 64 + lane;
            float vx = xb[n * FF + 3], vy = xb[n * FF + 4];
            float sp = sqrtf(fmaf(vx, vx, vy * vy));
            sp = wave_sum(sp);
            if (lane == 0) spd[b * 16 + jg] = sp;
        }
        {   // MLP layer-1 partial: one 1792-elt chunk per wave (8192 total)
            int id = blk * 16 + w;
            int mb = id >> 8, mh = (id >> 2) & 63, mc = id & 3;
            const float4* wr = (const float4*)(Wm0 + mh * (NN * FF) + mc * 1792);
            const float4* xr = (const float4*)(x + mb * (NN * FF) + mc * 1792);
            float4 a4 = {0.f, 0.f, 0.f, 0.f};
#pragma unroll
            for (int it = 0; it < 7; ++it) {
                float4 wv = wr[it * 64 + lane];
                float4 xv = xr[it * 64 + lane];
                a4.x = fmaf(wv.x, xv.x, a4.x);
                a4.y = fmaf(wv.y, xv.y, a4.y);
                a4.z = fmaf(wv.z, xv.z, a4.z);
                a4.w = fmaf(wv.w, xv.w, a4.w);
            }
            float s = (a4.x + a4.y) + (a4.z + a4.w);
            s = wave_sum(s);
            if (lane == 0) mlp_p[id] = s;
        }
    } else {
        // weight collapse, one block per output row o (256 active threads).
        int o = blk - 512;
        if (tid < HID) l0[tid] = Wp[o * CATN + MLPH + tid];
        __syncthreads();
        if (tid < HID) {
            float a = 0.f;
#pragma unroll 8
            for (int m = 0; m < HID; ++m) a = fmaf(l0[m], Wfc[m * HID + tid], a);
            l1[tid] = a;
            red[tid] = l0[tid] * bfc[tid];
        }
        __syncthreads();
        if (tid < HID) {
            float e = 0.f;
#pragma unroll 8
            for (int k = 0; k < HID; ++k) e = fmaf(l1[k], W2[k * HID + tid], e);
            E[o * HID + tid] = e;
            float c = fmaf(l1[tid], b2[tid], red[tid]);
            c = wave_sum(c);
            if (lane == 0) wred[w] = c;
        }
        __syncthreads();
        if (tid == 0) cE[o] = wred[0] + wred[1] + wred[2] + wred[3];
    }
}

// kB: pass2, same 512x1024 structure. FINAL q0/q1/wj per (b,j).
__global__ __launch_bounds__(1024, 8) void kB(const float* __restrict__ x,
                                              const float* __restrict__ deg,
                                              float* __restrict__ q0,
                                              float* __restrict__ q1,
                                              float* __restrict__ wj) {
    __shared__ __align__(16) float l0[NN];
    __shared__ __align__(16) float l1[NN];
    __shared__ __align__(16) float di[NN];
    __shared__ __align__(16) float r0[NN];
    __shared__ __align__(16) float r1[NN];
    __shared__ __align__(16) float r2[NN];
    int blk = blockIdx.x, tid = threadIdx.x, lane = tid & 63, w = tid >> 6;
    int b = blk >> 4, jg = blk & 15;
    const float* xb = x + b * (NN * FF);
    l0[tid] = xb[tid * FF + 1];
    l1[tid] = xb[tid * FF + 2];
    di[tid] = 1.0f / sqrtf(deg[b * NN + tid]);
    __syncthreads();
    int j = jg * 64 + lane;
    float pj0 = l0[j], pj1 = l1[j];
    const float4* v0p = (const float4*)&l0[w * 64];
    const float4* v1p = (const float4*)&l1[w * 64];
    const float4* vdp = (const float4*)&di[w * 64];
    float a0 = 0.f, a1 = 0.f, as = 0.f;
#pragma unroll 4
    for (int g = 0; g < 16; ++g) {
        float4 v0 = v0p[g], v1 = v1p[g], vd = vdp[g];
        float dxa = pj0 - v0.x, dya = pj1 - v1.x;
        float dxb = pj0 - v0.y, dyb = pj1 - v1.y;
        float dxc = pj0 - v0.z, dyc = pj1 - v1.z;
        float dxd = pj0 - v0.w, dyd = pj1 - v1.w;
        float da = fmaf(dya, dya, dxa * dxa);
        float db = fmaf(dyb, dyb, dxb * dxb);
        float dc = fmaf(dyc, dyc, dxc * dxc);
        float dd = fmaf(dyd, dyd, dxd * dxd);
        float ta = (da <= 0.09f) ? vd.x : 0.0f;
        float tb = (db <= 0.09f) ? vd.y : 0.0f;
        float tc = (dc <= 0.09f) ? vd.z : 0.0f;
        float td = (dd <= 0.09f) ? vd.w : 0.0f;
        a0 = fmaf(ta, v0.x, a0); a1 = fmaf(ta, v1.x, a1); as += ta;
        a0 = fmaf(tb, v0.y, a0); a1 = fmaf(tb, v1.y, a1); as += tb;
        a0 = fmaf(tc, v0.z, a0); a1 = fmaf(tc, v1.z, a1); as += tc;
        a0 = fmaf(td, v0.w, a0); a1 = fmaf(td, v1.w, a1); as += td;
    }
    r0[tid] = a0; r1[tid] = a1; r2[tid] = as;
    __syncthreads();
    if (tid < 64) {
        float s0 = 0.f, s1 = 0.f, ss = 0.f;
#pragma unroll
        for (int kk = 0; kk < 16; ++kk) {
            s0 += r0[kk * 64 + tid];
            s1 += r1[kk * 64 + tid];
            ss += r2[kk * 64 + tid];
        }
        int jj = jg * 64 + tid;
        float dj = di[jj];
        q0[b * NN + jj] = dj * s0;
        q1[b * NN + jj] = dj * s1;
        wj[b * NN + jj] = dj * ss * (1.0f / NN);
    }
}

// kF: hsum + collapsed epilogue. 32 blocks x 1024.
__global__ __launch_bounds__(1024, 4) void kF(const float* __restrict__ q0,
                                              const float* __restrict__ q1,
                                              const float* __restrict__ wj,
                                              const float* __restrict__ W1,
                                              const float* __restrict__ b1,
                                              const float* __restrict__ Wg,
                                              const float* __restrict__ bg,
                                              const float* __restrict__ Wm1,
                                              const float* __restrict__ bm1,
                                              const float* __restrict__ Wp,
                                              const float* __restrict__ bp,
                                              const float* __restrict__ bm0,
                                              const float* __restrict__ mlp_p,
                                              const float* __restrict__ bmaxp,
                                              const float* __restrict__ spd,
                                              const float* __restrict__ E,
                                              const float* __restrict__ cE,
                                              float* __restrict__ out) {
    __shared__ __align__(16) float sq0[NN];
    __shared__ __align__(16) float sq1[NN];
    __shared__ __align__(16) float sw[NN];
    __shared__ __align__(16) float hpp[4][HID];
    __shared__ __align__(16) float hs[HID];
    __shared__ float sx1[MLPH];
    __shared__ float sxf2[MLPH];
    __shared__ float sglo[8];
    int b = blockIdx.x, tid = threadIdx.x;
    // stage A: stage q/w; side roles on spare thread ranges
    sq0[tid] = q0[b * NN + tid];
    sq1[tid] = q1[b * NN + tid];
    sw[tid]  = wj[b * NN + tid];
    if (tid >= 448 && tid < 512) {   // xf1 = relu(sum of 4 mlp chunks + bm0)
        int h = tid - 448;
        float4 p = *(const float4*)&mlp_p[b * 256 + h * 4];
        sx1[h] = fmaxf(((p.x + p.y) + (p.z + p.w)) + bm0[h], 0.f);
    }
    __syncthreads();
    // stage B: hsum, 4-way j-parallel
    {
        int h = tid & 255, jq = tid >> 8;
        float w10 = W1[h * 2], w11 = W1[h * 2 + 1], bb = b1[h];
        float acc = 0.f;
        const float4* q0v4 = (const float4*)&sq0[jq * 256];
        const float4* q1v4 = (const float4*)&sq1[jq * 256];
        const float4* wv4  = (const float4*)&sw[jq * 256];
#pragma unroll 4
        for (int g = 0; g < 64; ++g) {
            float4 q0v = q0v4[g], q1v = q1v4[g], wv = wv4[g];
            acc = fmaf(wv.x, fmaxf(fmaf(q1v.x, w11, fmaf(q0v.x, w10, bb)), 0.f), acc);
            acc = fmaf(wv.y, fmaxf(fmaf(q1v.y, w11, fmaf(q0v.y, w10, bb)), 0.f), acc);
            acc = fmaf(wv.z, fmaxf(fmaf(q1v.z, w11, fmaf(q0v.z, w10, bb)), 0.f), acc);
            acc = fmaf(wv.w, fmaxf(fmaf(q1v.w, w11, fmaf(q0v.w, w10, bb)), 0.f), acc);
        }
        hpp[jq][h] = acc;
    }
    __syncthreads();
    // stage C: hs reduce (0..255); MLP layer-2 (256..319); global branch (320..327)
    if (tid < HID) {
        hs[tid] = hpp[0][tid] + hpp[1][tid] + hpp[2][tid] + hpp[3][tid];
    } else if (tid < HID + MLPH) {
        int t = tid - HID;
        float a = bm1[t];
        const float* wv = Wm1 + t * MLPH;
#pragma unroll
        for (int k = 0; k < MLPH; ++k) a = fmaf(wv[k], sx1[k], a);
        sxf2[t] = fmaxf(a, 0.f);
    } else if (tid < HID + MLPH + 8) {
        int t = tid - HID - MLPH;
        float mx = 0.f, sp = 0.f;
#pragma unroll
        for (int g = 0; g < 16; ++g) {
            mx = fmaxf(mx, bmaxp[b * 16 + g]);
            sp += spd[b * 16 + g];
        }
        float avg  = sp * (1.0f / NN);
        float dens = 1.0f / sqrtf(mx);
        sglo[t] = fmaxf(fmaf(Wg[t * 2], avg, fmaf(Wg[t * 2 + 1], dens, bg[t])), 0.f);
    }
    __syncthreads();
    // stage D: one wave per output o
    if (tid < 512) {
        int o = tid >> 6, lane = tid & 63;
        const float* Eo = E + o * HID;
        float a = Eo[lane] * hs[lane];
        a = fmaf(Eo[lane + 64],  hs[lane + 64],  a);
        a = fmaf(Eo[lane + 128], hs[lane + 128], a);
        a = fmaf(Eo[lane + 192], hs[lane + 192], a);
        a = fmaf(Wp[o * CATN + lane], sxf2[lane], a);
        a = wave_sum(a);
        if (lane == 0) {
            const float* wg = Wp + o * CATN + MLPH + HID;
#pragma unroll
            for (int g = 0; g < 8; ++g) a = fmaf(wg[g], sglo[g], a);
            out[b * OUTN + o] = a + cE[o] + bp[o];
        }
    }
}

extern "C" void kernel_launch(void* const* d_in, const int* in_sizes, int n_in,
                              void* d_out, int out_size, void* d_ws, size_t ws_size,
                              hipStream_t stream) {
    const float* x   = (const float*)d_in[0];
    const float* W1  = (const float*)d_in[1];
    const float* b1  = (const float*)d_in[2];
    const float* W2  = (const float*)d_in[3];
    const float* b2  = (const float*)d_in[4];
    const float* Wfc = (const float*)d_in[5];
    const float* bfc = (const float*)d_in[6];
    const float* Wg  = (const float*)d_in[7];
    const float* bg  = (const float*)d_in[8];
    const float* Wm0 = (const float*)d_in[9];
    const float* bm0 = (const float*)d_in[10];
    const float* Wm1 = (const float*)d_in[11];
    const float* bm1 = (const float*)d_in[12];
    const float* Wp  = (const float*)d_in[13];
    const float* bp  = (const float*)d_in[14];
    float* out = (float*)d_out;
    float* ws  = (float*)d_ws;

    float* deg   = ws;            // 32*1024 = 32768
    float* q0    = ws + 32768;    // 32768
    float* q1    = ws + 65536;    // 32768
    float* wj    = ws + 98304;    // 32768
    float* mlp_p = ws + 131072;   // 8192
    float* bmaxp = ws + 139264;   // 512
    float* spd   = ws + 139776;   // 512
    float* E     = ws + 140288;   // 2048
    float* cE    = ws + 142336;   // 8
    // every ws cell is written before it is read -> no zero-init needed.

    kA<<<520, 1024, 0, stream>>>(x, Wm0, W2, b2, Wfc, bfc, Wp,
                                 deg, bmaxp, spd, mlp_p, E, cE);
    kB<<<512, 1024, 0, stream>>>(x, deg, q0, q1, wj);
    kF<<<BB,  1024, 0, stream>>>(q0, q1, wj, W1, b1, Wg, bg, Wm1, bm1, Wp, bp,
                                 bm0, mlp_p, bmaxp, spd, E, cE, out);
}

// Round 9
// 129.599 us; speedup vs baseline: 2.3881x; 1.0218x over previous
//
#include <hip/hip_runtime.h>

#define BB 32
#define NN 1024
#define FF 7
#define HID 256
#define MLPH 64
#define OUTN 8
#define CATN (MLPH + HID + 8)   // 328

__device__ __forceinline__ float wave_sum(float v) {
#pragma unroll
    for (int m = 32; m >= 1; m >>= 1) v += __shfl_xor(v, m, 64);
    return v;
}
__device__ __forceinline__ float wave_max(float v) {
#pragma unroll
    for (int m = 32; m >= 1; m >>= 1) v = fmaxf(v, __shfl_xor(v, m, 64));
    return v;
}

// kA: blocks [0,256): pass1 unit (b = blk>>3, jg = blk&7) — 128 j x 1024 k,
//     2 j per thread (each LDS broadcast read serves 8 pairs). ONE round on 256 CUs.
//     blocks [256,384): MLP layer-1 GEMV, one wave per (b,h) full row.
//     blocks [384,392): weight collapse E = (Wp_gcn@Wfc)@W2, cE.
__global__ __launch_bounds__(1024, 4) void kA(const float* __restrict__ x,
                                              const float* __restrict__ Wm0,
                                              const float* __restrict__ W2,
                                              const float* __restrict__ b2,
                                              const float* __restrict__ Wfc,
                                              const float* __restrict__ bfc,
                                              const float* __restrict__ Wp,
                                              float* __restrict__ deg,
                                              float* __restrict__ bmaxp,
                                              float* __restrict__ spd,
                                              float* __restrict__ mlp_p,
                                              float* __restrict__ E,
                                              float* __restrict__ cE) {
    __shared__ __align__(16) float l0[NN];
    __shared__ __align__(16) float l1[NN];
    __shared__ __align__(16) float s2[NN];
    __shared__ __align__(16) float s3[NN];
    __shared__ float wred[16];
    int blk = blockIdx.x, tid = threadIdx.x, lane = tid & 63, w = tid >> 6;
    if (blk < 256) {
        int b = blk >> 3, jg = blk & 7;
        const float* xb = x + b * (NN * FF);
        l0[tid] = xb[tid * FF + 1];
        l1[tid] = xb[tid * FF + 2];
        __syncthreads();
        int jA = jg * 128 + lane, jB = jA + 64;
        float pj0a = l0[jA], pj1a = l1[jA];
        float pj0b = l0[jB], pj1b = l1[jB];
        const float4* v0p = (const float4*)&l0[w * 64];   // wave w owns k-chunk w
        const float4* v1p = (const float4*)&l1[w * 64];
        unsigned dA = 0u, dB = 0u;
        float mx = 0.f;
#pragma unroll 4
        for (int g = 0; g < 16; ++g) {
            float4 v0 = v0p[g], v1 = v1p[g];
            float dx, dy, d2a, d2b;
            dx = pj0a - v0.x; dy = pj1a - v1.x; d2a = fmaf(dy, dy, dx * dx);
            dx = pj0b - v0.x; dy = pj1b - v1.x; d2b = fmaf(dy, dy, dx * dx);
            dA += (d2a <= 0.09f); dB += (d2b <= 0.09f);
            mx = fmaxf(mx, fmaxf(d2a, d2b));
            dx = pj0a - v0.y; dy = pj1a - v1.y; d2a = fmaf(dy, dy, dx * dx);
            dx = pj0b - v0.y; dy = pj1b - v1.y; d2b = fmaf(dy, dy, dx * dx);
            dA += (d2a <= 0.09f); dB += (d2b <= 0.09f);
            mx = fmaxf(mx, fmaxf(d2a, d2b));
            dx = pj0a - v0.z; dy = pj1a - v1.z; d2a = fmaf(dy, dy, dx * dx);
            dx = pj0b - v0.z; dy = pj1b - v1.z; d2b = fmaf(dy, dy, dx * dx);
            dA += (d2a <= 0.09f); dB += (d2b <= 0.09f);
            mx = fmaxf(mx, fmaxf(d2a, d2b));
            dx = pj0a - v0.w; dy = pj1a - v1.w; d2a = fmaf(dy, dy, dx * dx);
            dx = pj0b - v0.w; dy = pj1b - v1.w; d2b = fmaf(dy, dy, dx * dx);
            dA += (d2a <= 0.09f); dB += (d2b <= 0.09f);
            mx = fmaxf(mx, fmaxf(d2a, d2b));
        }
        s2[tid] = (float)dA;
        s3[tid] = (float)dB;
        mx = wave_max(mx);
        if (lane == 0) wred[w] = mx;
        __syncthreads();
        if (tid < 64) {
            float s = 0.f;
#pragma unroll
            for (int kk = 0; kk < 16; ++kk) s += s2[kk * 64 + tid];
            deg[b * NN + jg * 128 + tid] = s;
        } else if (tid < 128) {
            int t = tid - 64;
            float s = 0.f;
#pragma unroll
            for (int kk = 0; kk < 16; ++kk) s += s3[kk * 64 + t];
            deg[b * NN + jg * 128 + 64 + t] = s;
        }
        if (tid == 0) {
            float m = wred[0];
#pragma unroll
            for (int i = 1; i < 16; ++i) m = fmaxf(m, wred[i]);
            bmaxp[b * 8 + jg] = m;
        }
        if (jg == 0) {   // block (b,0) owns the per-batch speed sum (1024 nodes)
            float vx = xb[tid * FF + 3], vy = xb[tid * FF + 4];
            float sp = sqrtf(fmaf(vx, vx, vy * vy));
            sp = wave_sum(sp);
            __syncthreads();   // wred (bmax) fully consumed above
            if (lane == 0) wred[w] = sp;
            __syncthreads();
            if (tid == 0) {
                float s = 0.f;
#pragma unroll
                for (int i = 0; i < 16; ++i) s += wred[i];
                spd[b] = s;
            }
        }
    } else if (blk < 384) {
        // MLP layer-1: one wave per (b,h) full 7168-row dot.
        int gid = (blk - 256) * 16 + w;          // [0,2048)  == b*64 + h
        int b = gid >> 6, h = gid & 63;
        const float4* wr = (const float4*)(Wm0 + h * (NN * FF));
        const float4* xr = (const float4*)(x + b * (NN * FF));
        float4 a4 = {0.f, 0.f, 0.f, 0.f};
#pragma unroll 7
        for (int it = 0; it < 28; ++it) {
            float4 wv = wr[it * 64 + lane];
            float4 xv = xr[it * 64 + lane];
            a4.x = fmaf(wv.x, xv.x, a4.x);
            a4.y = fmaf(wv.y, xv.y, a4.y);
            a4.z = fmaf(wv.z, xv.z, a4.z);
            a4.w = fmaf(wv.w, xv.w, a4.w);
        }
        float s = (a4.x + a4.y) + (a4.z + a4.w);
        s = wave_sum(s);
        if (lane == 0) mlp_p[gid] = s;
    } else {
        // weight collapse, one block per output row o (256 active threads).
        int o = blk - 384;
        if (tid < HID) l0[tid] = Wp[o * CATN + MLPH + tid];
        __syncthreads();
        if (tid < HID) {
            float a = 0.f;
#pragma unroll 8
            for (int m = 0; m < HID; ++m) a = fmaf(l0[m], Wfc[m * HID + tid], a);
            l1[tid] = a;
            s2[tid] = l0[tid] * bfc[tid];
        }
        __syncthreads();
        if (tid < HID) {
            float e = 0.f;
#pragma unroll 8
            for (int k = 0; k < HID; ++k) e = fmaf(l1[k], W2[k * HID + tid], e);
            E[o * HID + tid] = e;
            float c = fmaf(l1[tid], b2[tid], s2[tid]);
            c = wave_sum(c);
            if (lane == 0) wred[w] = c;
        }
        __syncthreads();
        if (tid == 0) cE[o] = wred[0] + wred[1] + wred[2] + wred[3];
    }
}

// kB: pass2, 256 blocks x 1024 thr, 2 j per thread, ONE round. FINAL q0/q1/wj.
__global__ __launch_bounds__(1024, 4) void kB(const float* __restrict__ x,
                                              const float* __restrict__ deg,
                                              float* __restrict__ q0,
                                              float* __restrict__ q1,
                                              float* __restrict__ wj) {
    __shared__ __align__(16) float l0[NN];
    __shared__ __align__(16) float l1[NN];
    __shared__ __align__(16) float di[NN];
    __shared__ __align__(16) float r0a[NN];
    __shared__ __align__(16) float r1a[NN];
    __shared__ __align__(16) float r2a[NN];
    __shared__ __align__(16) float r0b[NN];
    __shared__ __align__(16) float r1b[NN];
    __shared__ __align__(16) float r2b[NN];
    int blk = blockIdx.x, tid = threadIdx.x, lane = tid & 63, w = tid >> 6;
    int b = blk >> 3, jg = blk & 7;
    const float* xb = x + b * (NN * FF);
    l0[tid] = xb[tid * FF + 1];
    l1[tid] = xb[tid * FF + 2];
    di[tid] = 1.0f / sqrtf(deg[b * NN + tid]);
    __syncthreads();
    int jA = jg * 128 + lane, jB = jA + 64;
    float pj0a = l0[jA], pj1a = l1[jA];
    float pj0b = l0[jB], pj1b = l1[jB];
    const float4* v0p = (const float4*)&l0[w * 64];
    const float4* v1p = (const float4*)&l1[w * 64];
    const float4* vdp = (const float4*)&di[w * 64];
    float a0a = 0.f, a1a = 0.f, asa = 0.f;
    float a0b = 0.f, a1b = 0.f, asb = 0.f;
#pragma unroll 4
    for (int g = 0; g < 16; ++g) {
        float4 v0 = v0p[g], v1 = v1p[g], vd = vdp[g];
        float dx, dy, d2, t;
        dx = pj0a - v0.x; dy = pj1a - v1.x; d2 = fmaf(dy, dy, dx * dx);
        t = (d2 <= 0.09f) ? vd.x : 0.0f;
        a0a = fmaf(t, v0.x, a0a); a1a = fmaf(t, v1.x, a1a); asa += t;
        dx = pj0b - v0.x; dy = pj1b - v1.x; d2 = fmaf(dy, dy, dx * dx);
        t = (d2 <= 0.09f) ? vd.x : 0.0f;
        a0b = fmaf(t, v0.x, a0b); a1b = fmaf(t, v1.x, a1b); asb += t;
        dx = pj0a - v0.y; dy = pj1a - v1.y; d2 = fmaf(dy, dy, dx * dx);
        t = (d2 <= 0.09f) ? vd.y : 0.0f;
        a0a = fmaf(t, v0.y, a0a); a1a = fmaf(t, v1.y, a1a); asa += t;
        dx = pj0b - v0.y; dy = pj1b - v1.y; d2 = fmaf(dy, dy, dx * dx);
        t = (d2 <= 0.09f) ? vd.y : 0.0f;
        a0b = fmaf(t, v0.y, a0b); a1b = fmaf(t, v1.y, a1b); asb += t;
        dx = pj0a - v0.z; dy = pj1a - v1.z; d2 = fmaf(dy, dy, dx * dx);
        t = (d2 <= 0.09f) ? vd.z : 0.0f;
        a0a = fmaf(t, v0.z, a0a); a1a = fmaf(t, v1.z, a1a); asa += t;
        dx = pj0b - v0.z; dy = pj1b - v1.z; d2 = fmaf(dy, dy, dx * dx);
        t = (d2 <= 0.09f) ? vd.z : 0.0f;
        a0b = fmaf(t, v0.z, a0b); a1b = fmaf(t, v1.z, a1b); asb += t;
        dx = pj0a - v0.w; dy = pj1a - v1.w; d2 = fmaf(dy, dy, dx * dx);
        t = (d2 <= 0.09f) ? vd.w : 0.0f;
        a0a = fmaf(t, v0.w, a0a); a1a = fmaf(t, v1.w, a1a); asa += t;
        dx = pj0b - v0.w; dy = pj1b - v1.w; d2 = fmaf(dy, dy, dx * dx);
        t = (d2 <= 0.09f) ? vd.w : 0.0f;
        a0b = fmaf(t, v0.w, a0b); a1b = fmaf(t, v1.w, a1b); asb += t;
    }
    r0a[tid] = a0a; r1a[tid] = a1a; r2a[tid] = asa;
    r0b[tid] = a0b; r1b[tid] = a1b; r2b[tid] = asb;
    __syncthreads();
    if (tid < 128) {
        int t = tid & 63;
        const float* R0 = (tid < 64) ? r0a : r0b;
        const float* R1 = (tid < 64) ? r1a : r1b;
        const float* R2 = (tid < 64) ? r2a : r2b;
        int j = jg * 128 + ((tid < 64) ? 0 : 64) + t;
        float s0 = 0.f, s1 = 0.f, ss = 0.f;
#pragma unroll
        for (int kk = 0; kk < 16; ++kk) {
            s0 += R0[kk * 64 + t];
            s1 += R1[kk * 64 + t];
            ss += R2[kk * 64 + t];
        }
        float dj = di[j];
        q0[b * NN + j] = dj * s0;
        q1[b * NN + j] = dj * s1;
        wj[b * NN + j] = dj * ss * (1.0f / NN);
    }
}

// kF: hsum + collapsed epilogue. 32 blocks x 1024.
__global__ __launch_bounds__(1024, 4) void kF(const float* __restrict__ q0,
                                              const float* __restrict__ q1,
                                              const float* __restrict__ wj,
                                              const float* __restrict__ W1,
                                              const float* __restrict__ b1,
                                              const float* __restrict__ Wg,
                                              const float* __restrict__ bg,
                                              const float* __restrict__ Wm1,
                                              const float* __restrict__ bm1,
                                              const float* __restrict__ Wp,
                                              const float* __restrict__ bp,
                                              const float* __restrict__ bm0,
                                              const float* __restrict__ mlp_p,
                                              const float* __restrict__ bmaxp,
                                              const float* __restrict__ spd,
                                              const float* __restrict__ E,
                                              const float* __restrict__ cE,
                                              float* __restrict__ out) {
    __shared__ __align__(16) float sq0[NN];
    __shared__ __align__(16) float sq1[NN];
    __shared__ __align__(16) float sw[NN];
    __shared__ __align__(16) float hpp[4][HID];
    __shared__ __align__(16) float hs[HID];
    __shared__ float sx1[MLPH];
    __shared__ float sxf2[MLPH];
    __shared__ float sglo[8];
    int b = blockIdx.x, tid = threadIdx.x;
    sq0[tid] = q0[b * NN + tid];
    sq1[tid] = q1[b * NN + tid];
    sw[tid]  = wj[b * NN + tid];
    if (tid >= 448 && tid < 512) {   // xf1 = relu(mlp row dot + bm0)
        int h = tid - 448;
        sx1[h] = fmaxf(mlp_p[b * MLPH + h] + bm0[h], 0.f);
    }
    __syncthreads();
    {   // hsum, 4-way j-parallel
        int h = tid & 255, jq = tid >> 8;
        float w10 = W1[h * 2], w11 = W1[h * 2 + 1], bb = b1[h];
        float acc = 0.f;
        const float4* q0v4 = (const float4*)&sq0[jq * 256];
        const float4* q1v4 = (const float4*)&sq1[jq * 256];
        const float4* wv4  = (const float4*)&sw[jq * 256];
#pragma unroll 4
        for (int g = 0; g < 64; ++g) {
            float4 q0v = q0v4[g], q1v = q1v4[g], wv = wv4[g];
            acc = fmaf(wv.x, fmaxf(fmaf(q1v.x, w11, fmaf(q0v.x, w10, bb)), 0.f), acc);
            acc = fmaf(wv.y, fmaxf(fmaf(q1v.y, w11, fmaf(q0v.y, w10, bb)), 0.f), acc);
            acc = fmaf(wv.z, fmaxf(fmaf(q1v.z, w11, fmaf(q0v.z, w10, bb)), 0.f), acc);
            acc = fmaf(wv.w, fmaxf(fmaf(q1v.w, w11, fmaf(q0v.w, w10, bb)), 0.f), acc);
        }
        hpp[jq][h] = acc;
    }
    __syncthreads();
    if (tid < HID) {
        hs[tid] = hpp[0][tid] + hpp[1][tid] + hpp[2][tid] + hpp[3][tid];
    } else if (tid < HID + MLPH) {
        int t = tid - HID;
        float a = bm1[t];
        const float* wv = Wm1 + t * MLPH;
#pragma unroll
        for (int k = 0; k < MLPH; ++k) a = fmaf(wv[k], sx1[k], a);
        sxf2[t] = fmaxf(a, 0.f);
    } else if (tid < HID + MLPH + 8) {
        int t = tid - HID - MLPH;
        float mx = 0.f;
#pragma unroll
        for (int g = 0; g < 8; ++g) mx = fmaxf(mx, bmaxp[b * 8 + g]);
        float avg  = spd[b] * (1.0f / NN);
        float dens = 1.0f / sqrtf(mx);
        sglo[t] = fmaxf(fmaf(Wg[t * 2], avg, fmaf(Wg[t * 2 + 1], dens, bg[t])), 0.f);
    }
    __syncthreads();
    if (tid < 512) {
        int o = tid >> 6, lane = tid & 63;
        const float* Eo = E + o * HID;
        float a = Eo[lane] * hs[lane];
        a = fmaf(Eo[lane + 64],  hs[lane + 64],  a);
        a = fmaf(Eo[lane + 128], hs[lane + 128], a);
        a = fmaf(Eo[lane + 192], hs[lane + 192], a);
        a = fmaf(Wp[o * CATN + lane], sxf2[lane], a);
        a = wave_sum(a);
        if (lane == 0) {
            const float* wg = Wp + o * CATN + MLPH + HID;
#pragma unroll
            for (int g = 0; g < 8; ++g) a = fmaf(wg[g], sglo[g], a);
            out[b * OUTN + o] = a + cE[o] + bp[o];
        }
    }
}

extern "C" void kernel_launch(void* const* d_in, const int* in_sizes, int n_in,
                              void* d_out, int out_size, void* d_ws, size_t ws_size,
                              hipStream_t stream) {
    const float* x   = (const float*)d_in[0];
    const float* W1  = (const float*)d_in[1];
    const float* b1  = (const float*)d_in[2];
    const float* W2  = (const float*)d_in[3];
    const float* b2  = (const float*)d_in[4];
    const float* Wfc = (const float*)d_in[5];
    const float* bfc = (const float*)d_in[6];
    const float* Wg  = (const float*)d_in[7];
    const float* bg  = (const float*)d_in[8];
    const float* Wm0 = (const float*)d_in[9];
    const float* bm0 = (const float*)d_in[10];
    const float* Wm1 = (const float*)d_in[11];
    const float* bm1 = (const float*)d_in[12];
    const float* Wp  = (const float*)d_in[13];
    const float* bp  = (const float*)d_in[14];
    float* out = (float*)d_out;
    float* ws  = (float*)d_ws;

    float* deg   = ws;            // 32768
    float* q0    = ws + 32768;    // 32768
    float* q1    = ws + 65536;    // 32768
    float* wj    = ws + 98304;    // 32768
    float* mlp_p = ws + 131072;   // 2048
    float* bmaxp = ws + 133120;   // 256
    float* spd   = ws + 133376;   // 32
    float* E     = ws + 133408;   // 2048
    float* cE    = ws + 135456;   // 8
    // every ws cell is written before it is read -> no zero-init needed.

    kA<<<392, 1024, 0, stream>>>(x, Wm0, W2, b2, Wfc, bfc, Wp,
                                 deg, bmaxp, spd, mlp_p, E, cE);
    kB<<<256, 1024, 0, stream>>>(x, deg, q0, q1, wj);
    kF<<<BB,  1024, 0, stream>>>(q0, q1, wj, W1, b1, Wg, bg, Wm1, bm1, Wp, bp,
                                 bm0, mlp_p, bmaxp, spd, E, cE, out);
}

// Round 10
// 128.532 us; speedup vs baseline: 2.4079x; 1.0083x over previous
//
#include <hip/hip_runtime.h>

#define BB 32
#define NN 1024
#define FF 7
#define HID 256
#define MLPH 64
#define OUTN 8
#define CATN (MLPH + HID + 8)   // 328

__device__ __forceinline__ float wave_sum(float v) {
#pragma unroll
    for (int m = 32; m >= 1; m >>= 1) v += __shfl_xor(v, m, 64);
    return v;
}
__device__ __forceinline__ float wave_max(float v) {
#pragma unroll
    for (int m = 32; m >= 1; m >>= 1) v = fmaxf(v, __shfl_xor(v, m, 64));
    return v;
}

// kPM: blocks [0,32): repack x -> pts SoA (coalesced, x read ONCE) + speed sum.
//      blocks [32,40): weight collapse E = (Wp_gcn@Wfc)@W2, cE.
//      blocks [40,104): MLP-L1 GEMV — one block per h, Wm0 row staged in LDS
//      (Wm0 read ONCE), loop over all 32 b (x rows served from L2).
__global__ __launch_bounds__(1024, 4) void kPM(const float* __restrict__ x,
                                               const float* __restrict__ Wm0,
                                               const float* __restrict__ W2,
                                               const float* __restrict__ b2,
                                               const float* __restrict__ Wfc,
                                               const float* __restrict__ bfc,
                                               const float* __restrict__ Wp,
                                               float* __restrict__ pts0,
                                               float* __restrict__ pts1,
                                               float* __restrict__ spd,
                                               float* __restrict__ mlp_p,
                                               float* __restrict__ E,
                                               float* __restrict__ cE) {
    __shared__ __align__(16) float sbuf[NN * FF];   // 28 KB
    __shared__ float wred[16];
    int blk = blockIdx.x, tid = threadIdx.x, lane = tid & 63, w = tid >> 6;
    if (blk < 32) {
        int b = blk;
        const float4* xr = (const float4*)(x + b * (NN * FF));
        float4* s4 = (float4*)sbuf;
        for (int i = tid; i < 1792; i += 1024) s4[i] = xr[i];   // coalesced stream
        __syncthreads();
        pts0[b * NN + tid] = sbuf[tid * FF + 1];   // LDS extract, global coalesced
        pts1[b * NN + tid] = sbuf[tid * FF + 2];
        float vx = sbuf[tid * FF + 3], vy = sbuf[tid * FF + 4];
        float sp = sqrtf(fmaf(vx, vx, vy * vy));
        sp = wave_sum(sp);
        if (lane == 0) wred[w] = sp;
        __syncthreads();
        if (tid == 0) {
            float s = 0.f;
#pragma unroll
            for (int i = 0; i < 16; ++i) s += wred[i];
            spd[b] = s;
        }
    } else if (blk < 40) {
        int o = blk - 32;
        float* l0 = sbuf;
        float* l1 = sbuf + 256;
        float* r2 = sbuf + 512;
        if (tid < HID) l0[tid] = Wp[o * CATN + MLPH + tid];
        __syncthreads();
        if (tid < HID) {
            float a = 0.f;
#pragma unroll 8
            for (int m = 0; m < HID; ++m) a = fmaf(l0[m], Wfc[m * HID + tid], a);
            l1[tid] = a;
            r2[tid] = l0[tid] * bfc[tid];
        }
        __syncthreads();
        if (tid < HID) {
            float e = 0.f;
#pragma unroll 8
            for (int k = 0; k < HID; ++k) e = fmaf(l1[k], W2[k * HID + tid], e);
            E[o * HID + tid] = e;
            float c = fmaf(l1[tid], b2[tid], r2[tid]);
            c = wave_sum(c);
            if (lane == 0) wred[w] = c;
        }
        __syncthreads();
        if (tid == 0) cE[o] = wred[0] + wred[1] + wred[2] + wred[3];
    } else {
        int h = blk - 40;
        const float4* wr = (const float4*)(Wm0 + h * (NN * FF));
        float4* s4 = (float4*)sbuf;
        for (int i = tid; i < 1792; i += 1024) s4[i] = wr[i];   // Wm0 row -> LDS once
        __syncthreads();
#pragma unroll
        for (int rep = 0; rep < 2; ++rep) {
            int b = w * 2 + rep;                 // each wave owns 2 batches
            const float4* xr = (const float4*)(x + b * (NN * FF));
            float4 a4 = {0.f, 0.f, 0.f, 0.f};
#pragma unroll 7
            for (int it = 0; it < 28; ++it) {
                float4 xv = xr[it * 64 + lane];
                float4 wv = s4[it * 64 + lane];
                a4.x = fmaf(wv.x, xv.x, a4.x);
                a4.y = fmaf(wv.y, xv.y, a4.y);
                a4.z = fmaf(wv.z, xv.z, a4.z);
                a4.w = fmaf(wv.w, xv.w, a4.w);
            }
            float s = (a4.x + a4.y) + (a4.z + a4.w);
            s = wave_sum(s);
            if (lane == 0) mlp_p[b * MLPH + h] = s;
        }
    }
}

// kA: pass1, 256 blocks (b = blk>>3, jg = blk&7), 128 j x 1024 k, 2 j/thread.
// Staging: 2 coalesced dword loads from compact pts SoA (8 KB/block).
__global__ __launch_bounds__(1024, 4) void kA(const float* __restrict__ pts0,
                                              const float* __restrict__ pts1,
                                              float* __restrict__ deg,
                                              float* __restrict__ bmaxp) {
    __shared__ __align__(16) float l0[NN];
    __shared__ __align__(16) float l1[NN];
    __shared__ __align__(16) float s2[NN];
    __shared__ __align__(16) float s3[NN];
    __shared__ float wred[16];
    int blk = blockIdx.x, tid = threadIdx.x, lane = tid & 63, w = tid >> 6;
    int b = blk >> 3, jg = blk & 7;
    l0[tid] = pts0[b * NN + tid];
    l1[tid] = pts1[b * NN + tid];
    __syncthreads();
    int jA = jg * 128 + lane, jB = jA + 64;
    float pj0a = l0[jA], pj1a = l1[jA];
    float pj0b = l0[jB], pj1b = l1[jB];
    const float4* v0p = (const float4*)&l0[w * 64];
    const float4* v1p = (const float4*)&l1[w * 64];
    unsigned dA = 0u, dB = 0u;
    float mx = 0.f;
#pragma unroll 4
    for (int g = 0; g < 16; ++g) {
        float4 v0 = v0p[g], v1 = v1p[g];
        float dx, dy, d2a, d2b;
        dx = pj0a - v0.x; dy = pj1a - v1.x; d2a = fmaf(dy, dy, dx * dx);
        dx = pj0b - v0.x; dy = pj1b - v1.x; d2b = fmaf(dy, dy, dx * dx);
        dA += (d2a <= 0.09f); dB += (d2b <= 0.09f);
        mx = fmaxf(mx, fmaxf(d2a, d2b));
        dx = pj0a - v0.y; dy = pj1a - v1.y; d2a = fmaf(dy, dy, dx * dx);
        dx = pj0b - v0.y; dy = pj1b - v1.y; d2b = fmaf(dy, dy, dx * dx);
        dA += (d2a <= 0.09f); dB += (d2b <= 0.09f);
        mx = fmaxf(mx, fmaxf(d2a, d2b));
        dx = pj0a - v0.z; dy = pj1a - v1.z; d2a = fmaf(dy, dy, dx * dx);
        dx = pj0b - v0.z; dy = pj1b - v1.z; d2b = fmaf(dy, dy, dx * dx);
        dA += (d2a <= 0.09f); dB += (d2b <= 0.09f);
        mx = fmaxf(mx, fmaxf(d2a, d2b));
        dx = pj0a - v0.w; dy = pj1a - v1.w; d2a = fmaf(dy, dy, dx * dx);
        dx = pj0b - v0.w; dy = pj1b - v1.w; d2b = fmaf(dy, dy, dx * dx);
        dA += (d2a <= 0.09f); dB += (d2b <= 0.09f);
        mx = fmaxf(mx, fmaxf(d2a, d2b));
    }
    s2[tid] = (float)dA;
    s3[tid] = (float)dB;
    mx = wave_max(mx);
    if (lane == 0) wred[w] = mx;
    __syncthreads();
    if (tid < 64) {
        float s = 0.f;
#pragma unroll
        for (int kk = 0; kk < 16; ++kk) s += s2[kk * 64 + tid];
        deg[b * NN + jg * 128 + tid] = s;
    } else if (tid < 128) {
        int t = tid - 64;
        float s = 0.f;
#pragma unroll
        for (int kk = 0; kk < 16; ++kk) s += s3[kk * 64 + t];
        deg[b * NN + jg * 128 + 64 + t] = s;
    }
    if (tid == 0) {
        float m = wred[0];
#pragma unroll
        for (int i = 1; i < 16; ++i) m = fmaxf(m, wred[i]);
        bmaxp[b * 8 + jg] = m;
    }
}

// kB: pass2, same structure, compact staging. FINAL q0/q1/wj.
__global__ __launch_bounds__(1024, 4) void kB(const float* __restrict__ pts0,
                                              const float* __restrict__ pts1,
                                              const float* __restrict__ deg,
                                              float* __restrict__ q0,
                                              float* __restrict__ q1,
                                              float* __restrict__ wj) {
    __shared__ __align__(16) float l0[NN];
    __shared__ __align__(16) float l1[NN];
    __shared__ __align__(16) float di[NN];
    __shared__ __align__(16) float r0a[NN];
    __shared__ __align__(16) float r1a[NN];
    __shared__ __align__(16) float r2a[NN];
    __shared__ __align__(16) float r0b[NN];
    __shared__ __align__(16) float r1b[NN];
    __shared__ __align__(16) float r2b[NN];
    int blk = blockIdx.x, tid = threadIdx.x, lane = tid & 63, w = tid >> 6;
    int b = blk >> 3, jg = blk & 7;
    l0[tid] = pts0[b * NN + tid];
    l1[tid] = pts1[b * NN + tid];
    di[tid] = 1.0f / sqrtf(deg[b * NN + tid]);
    __syncthreads();
    int jA = jg * 128 + lane, jB = jA + 64;
    float pj0a = l0[jA], pj1a = l1[jA];
    float pj0b = l0[jB], pj1b = l1[jB];
    const float4* v0p = (const float4*)&l0[w * 64];
    const float4* v1p = (const float4*)&l1[w * 64];
    const float4* vdp = (const float4*)&di[w * 64];
    float a0a = 0.f, a1a = 0.f, asa = 0.f;
    float a0b = 0.f, a1b = 0.f, asb = 0.f;
#pragma unroll 4
    for (int g = 0; g < 16; ++g) {
        float4 v0 = v0p[g], v1 = v1p[g], vd = vdp[g];
        float dx, dy, d2, t;
        dx = pj0a - v0.x; dy = pj1a - v1.x; d2 = fmaf(dy, dy, dx * dx);
        t = (d2 <= 0.09f) ? vd.x : 0.0f;
        a0a = fmaf(t, v0.x, a0a); a1a = fmaf(t, v1.x, a1a); asa += t;
        dx = pj0b - v0.x; dy = pj1b - v1.x; d2 = fmaf(dy, dy, dx * dx);
        t = (d2 <= 0.09f) ? vd.x : 0.0f;
        a0b = fmaf(t, v0.x, a0b); a1b = fmaf(t, v1.x, a1b); asb += t;
        dx = pj0a - v0.y; dy = pj1a - v1.y; d2 = fmaf(dy, dy, dx * dx);
        t = (d2 <= 0.09f) ? vd.y : 0.0f;
        a0a = fmaf(t, v0.y, a0a); a1a = fmaf(t, v1.y, a1a); asa += t;
        dx = pj0b - v0.y; dy = pj1b - v1.y; d2 = fmaf(dy, dy, dx * dx);
        t = (d2 <= 0.09f) ? vd.y : 0.0f;
        a0b = fmaf(t, v0.y, a0b); a1b = fmaf(t, v1.y, a1b); asb += t;
        dx = pj0a - v0.z; dy = pj1a - v1.z; d2 = fmaf(dy, dy, dx * dx);
        t = (d2 <= 0.09f) ? vd.z : 0.0f;
        a0a = fmaf(t, v0.z, a0a); a1a = fmaf(t, v1.z, a1a); asa += t;
        dx = pj0b - v0.z; dy = pj1b - v1.z; d2 = fmaf(dy, dy, dx * dx);
        t = (d2 <= 0.09f) ? vd.z : 0.0f;
        a0b = fmaf(t, v0.z, a0b); a1b = fmaf(t, v1.z, a1b); asb += t;
        dx = pj0a - v0.w; dy = pj1a - v1.w; d2 = fmaf(dy, dy, dx * dx);
        t = (d2 <= 0.09f) ? vd.w : 0.0f;
        a0a = fmaf(t, v0.w, a0a); a1a = fmaf(t, v1.w, a1a); asa += t;
        dx = pj0b - v0.w; dy = pj1b - v1.w; d2 = fmaf(dy, dy, dx * dx);
        t = (d2 <= 0.09f) ? vd.w : 0.0f;
        a0b = fmaf(t, v0.w, a0b); a1b = fmaf(t, v1.w, a1b); asb += t;
    }
    r0a[tid] = a0a; r1a[tid] = a1a; r2a[tid] = asa;
    r0b[tid] = a0b; r1b[tid] = a1b; r2b[tid] = asb;
    __syncthreads();
    if (tid < 128) {
        int t = tid & 63;
        const float* R0 = (tid < 64) ? r0a : r0b;
        const float* R1 = (tid < 64) ? r1a : r1b;
        const float* R2 = (tid < 64) ? r2a : r2b;
        int j = jg * 128 + ((tid < 64) ? 0 : 64) + t;
        float s0 = 0.f, s1 = 0.f, ss = 0.f;
#pragma unroll
        for (int kk = 0; kk < 16; ++kk) {
            s0 += R0[kk * 64 + t];
            s1 += R1[kk * 64 + t];
            ss += R2[kk * 64 + t];
        }
        float dj = di[j];
        q0[b * NN + j] = dj * s0;
        q1[b * NN + j] = dj * s1;
        wj[b * NN + j] = dj * ss * (1.0f / NN);
    }
}

// kF: hsum + collapsed epilogue. 32 blocks x 1024.
__global__ __launch_bounds__(1024, 4) void kF(const float* __restrict__ q0,
                                              const float* __restrict__ q1,
                                              const float* __restrict__ wj,
                                              const float* __restrict__ W1,
                                              const float* __restrict__ b1,
                                              const float* __restrict__ Wg,
                                              const float* __restrict__ bg,
                                              const float* __restrict__ Wm1,
                                              const float* __restrict__ bm1,
                                              const float* __restrict__ Wp,
                                              const float* __restrict__ bp,
                                              const float* __restrict__ bm0,
                                              const float* __restrict__ mlp_p,
                                              const float* __restrict__ bmaxp,
                                              const float* __restrict__ spd,
                                              const float* __restrict__ E,
                                              const float* __restrict__ cE,
                                              float* __restrict__ out) {
    __shared__ __align__(16) float sq0[NN];
    __shared__ __align__(16) float sq1[NN];
    __shared__ __align__(16) float sw[NN];
    __shared__ __align__(16) float hpp[4][HID];
    __shared__ __align__(16) float hs[HID];
    __shared__ float sx1[MLPH];
    __shared__ float sxf2[MLPH];
    __shared__ float sglo[8];
    int b = blockIdx.x, tid = threadIdx.x;
    sq0[tid] = q0[b * NN + tid];
    sq1[tid] = q1[b * NN + tid];
    sw[tid]  = wj[b * NN + tid];
    if (tid >= 448 && tid < 512) {   // xf1 = relu(mlp row dot + bm0)
        int h = tid - 448;
        sx1[h] = fmaxf(mlp_p[b * MLPH + h] + bm0[h], 0.f);
    }
    __syncthreads();
    {   // hsum, 4-way j-parallel
        int h = tid & 255, jq = tid >> 8;
        float w10 = W1[h * 2], w11 = W1[h * 2 + 1], bb = b1[h];
        float acc = 0.f;
        const float4* q0v4 = (const float4*)&sq0[jq * 256];
        const float4* q1v4 = (const float4*)&sq1[jq * 256];
        const float4* wv4  = (const float4*)&sw[jq * 256];
#pragma unroll 4
        for (int g = 0; g < 64; ++g) {
            float4 q0v = q0v4[g], q1v = q1v4[g], wv = wv4[g];
            acc = fmaf(wv.x, fmaxf(fmaf(q1v.x, w11, fmaf(q0v.x, w10, bb)), 0.f), acc);
            acc = fmaf(wv.y, fmaxf(fmaf(q1v.y, w11, fmaf(q0v.y, w10, bb)), 0.f), acc);
            acc = fmaf(wv.z, fmaxf(fmaf(q1v.z, w11, fmaf(q0v.z, w10, bb)), 0.f), acc);
            acc = fmaf(wv.w, fmaxf(fmaf(q1v.w, w11, fmaf(q0v.w, w10, bb)), 0.f), acc);
        }
        hpp[jq][h] = acc;
    }
    __syncthreads();
    if (tid < HID) {
        hs[tid] = hpp[0][tid] + hpp[1][tid] + hpp[2][tid] + hpp[3][tid];
    } else if (tid < HID + MLPH) {
        int t = tid - HID;
        float a = bm1[t];
        const float* wv = Wm1 + t * MLPH;
#pragma unroll
        for (int k = 0; k < MLPH; ++k) a = fmaf(wv[k], sx1[k], a);
        sxf2[t] = fmaxf(a, 0.f);
    } else if (tid < HID + MLPH + 8) {
        int t = tid - HID - MLPH;
        float mx = 0.f;
#pragma unroll
        for (int g = 0; g < 8; ++g) mx = fmaxf(mx, bmaxp[b * 8 + g]);
        float avg  = spd[b] * (1.0f / NN);
        float dens = 1.0f / sqrtf(mx);
        sglo[t] = fmaxf(fmaf(Wg[t * 2], avg, fmaf(Wg[t * 2 + 1], dens, bg[t])), 0.f);
    }
    __syncthreads();
    if (tid < 512) {
        int o = tid >> 6, lane = tid & 63;
        const float* Eo = E + o * HID;
        float a = Eo[lane] * hs[lane];
        a = fmaf(Eo[lane + 64],  hs[lane + 64],  a);
        a = fmaf(Eo[lane + 128], hs[lane + 128], a);
        a = fmaf(Eo[lane + 192], hs[lane + 192], a);
        a = fmaf(Wp[o * CATN + lane], sxf2[lane], a);
        a = wave_sum(a);
        if (lane == 0) {
            const float* wg = Wp + o * CATN + MLPH + HID;
#pragma unroll
            for (int g = 0; g < 8; ++g) a = fmaf(wg[g], sglo[g], a);
            out[b * OUTN + o] = a + cE[o] + bp[o];
        }
    }
}

extern "C" void kernel_launch(void* const* d_in, const int* in_sizes, int n_in,
                              void* d_out, int out_size, void* d_ws, size_t ws_size,
                              hipStream_t stream) {
    const float* x   = (const float*)d_in[0];
    const float* W1  = (const float*)d_in[1];
    const float* b1  = (const float*)d_in[2];
    const float* W2  = (const float*)d_in[3];
    const float* b2  = (const float*)d_in[4];
    const float* Wfc = (const float*)d_in[5];
    const float* bfc = (const float*)d_in[6];
    const float* Wg  = (const float*)d_in[7];
    const float* bg  = (const float*)d_in[8];
    const float* Wm0 = (const float*)d_in[9];
    const float* bm0 = (const float*)d_in[10];
    const float* Wm1 = (const float*)d_in[11];
    const float* bm1 = (const float*)d_in[12];
    const float* Wp  = (const float*)d_in[13];
    const float* bp  = (const float*)d_in[14];
    float* out = (float*)d_out;
    float* ws  = (float*)d_ws;

    float* pts0  = ws;            // 32768
    float* pts1  = ws + 32768;    // 32768
    float* deg   = ws + 65536;    // 32768
    float* q0    = ws + 98304;    // 32768
    float* q1    = ws + 131072;   // 32768
    float* wj    = ws + 163840;   // 32768
    float* mlp_p = ws + 196608;   // 2048
    float* bmaxp = ws + 198656;   // 256
    float* spd   = ws + 198912;   // 32
    float* E     = ws + 198944;   // 2048
    float* cE    = ws + 200992;   // 8
    // every ws cell is written before it is read -> no zero-init needed.

    kPM<<<104, 1024, 0, stream>>>(x, Wm0, W2, b2, Wfc, bfc, Wp,
                                  pts0, pts1, spd, mlp_p, E, cE);
    kA<<<256,  1024, 0, stream>>>(pts0, pts1, deg, bmaxp);
    kB<<<256,  1024, 0, stream>>>(pts0, pts1, deg, q0, q1, wj);
    kF<<<BB,   1024, 0, stream>>>(q0, q1, wj, W1, b1, Wg, bg, Wm1, bm1, Wp, bp,
                                  bm0, mlp_p, bmaxp, spd, E, cE, out);
}